// Round 9
// baseline (763.290 us; speedup 1.0000x reference)
//
#include <hip/hip_runtime.h>

// x[2048,64,2] -> MLP(2->16 relu ->16) -> 8x LSTM(H=64) -> MLP(64->32 relu ->4)
// fp32 in/out. LSTM via split-bf16 MFMA (3-term, ~fp32 accuracy).
//
// Round 9: two independent lockstep streams per CU.
//   M=4 rows/block, 256-thr blocks, grid 512, lb(256,2) -> 2 blocks/CU, each
//   with its own panel/barriers: two per-CU recurrence chains interleave.
//   Wave wv owns gate-block wv (n in [64wv,64wv+64), 4 n-tiles; KT x 8 frags).
//   Packed hi|lo u32 panel + v_perm unpack (r8-proven numerics), register
//   x-prefetch, full-lane phase C (1 slot/thread via gs), 2 barriers/step.

#define BATCH 2048
#define TT 64
#define GS  272   // gs row stride in floats (2-way-free)

typedef unsigned int u32;
typedef u32 u32x4 __attribute__((ext_vector_type(4)));
typedef short bf16x8 __attribute__((ext_vector_type(8)));
typedef float f32x4 __attribute__((ext_vector_type(4)));

__device__ __forceinline__ float sigmoid_fast(float x) {
    return __builtin_amdgcn_rcpf(1.f + __expf(-x));
}
__device__ __forceinline__ float tanh_fast(float x) {
    float e = __expf(-2.f * x);
    e = fminf(e, 1e30f);
    return (1.f - e) * __builtin_amdgcn_rcpf(1.f + e);
}
// fp32 -> (bf16 hi) | (bf16 lo of exact residual) << 16
__device__ __forceinline__ u32 pack_split(float x) {
    const u32 u = __float_as_uint(x);
    const float r = x - __uint_as_float(u & 0xFFFF0000u);
    return (u >> 16) | (__float_as_uint(r) & 0xFFFF0000u);
}
__device__ __forceinline__ void split2(float x, unsigned short& hi, unsigned short& lo) {
    const u32 u = __float_as_uint(x);
    hi = (unsigned short)(u >> 16);
    const float r = x - __uint_as_float(u & 0xFFFF0000u);
    lo = (unsigned short)(__float_as_uint(r) >> 16);
}
// 8 packed u32 -> hi-frag, lo-frag (bf16x8 each) via v_perm
__device__ __forceinline__ void unpack_frag(const u32x4 a, const u32x4 b, bf16x8& hi, bf16x8& lo) {
    union { bf16x8 v; u32 w[4]; } H, L;
    H.w[0] = __builtin_amdgcn_perm(a.y, a.x, 0x05040100u);
    H.w[1] = __builtin_amdgcn_perm(a.w, a.z, 0x05040100u);
    H.w[2] = __builtin_amdgcn_perm(b.y, b.x, 0x05040100u);
    H.w[3] = __builtin_amdgcn_perm(b.w, b.z, 0x05040100u);
    L.w[0] = __builtin_amdgcn_perm(a.y, a.x, 0x07060302u);
    L.w[1] = __builtin_amdgcn_perm(a.w, a.z, 0x07060302u);
    L.w[2] = __builtin_amdgcn_perm(b.y, b.x, 0x07060302u);
    L.w[3] = __builtin_amdgcn_perm(b.w, b.z, 0x07060302u);
    hi = H.v; lo = L.v;
}
__device__ __forceinline__ f32x4 mfma_bf16(bf16x8 a, bf16x8 b, f32x4 c) {
    return __builtin_amdgcn_mfma_f32_16x16x32_bf16(a, b, c, 0, 0, 0);
}

// ---------------- input MLP: 2 -> 16 relu -> 16 (packed hi/lo out) ----------------
__global__ __launch_bounds__(256)
void mlp_in_kernel(const float* __restrict__ x,
                   const float* __restrict__ w1, const float* __restrict__ b1,
                   const float* __restrict__ w2, const float* __restrict__ b2,
                   u32* __restrict__ out) {
    const int gid = blockIdx.x * 256 + threadIdx.x;
    const float x0 = x[gid * 2 + 0];
    const float x1 = x[gid * 2 + 1];
    float hid[16];
#pragma unroll
    for (int j = 0; j < 16; ++j) {
        float v = fmaf(x1, w1[j * 2 + 1], fmaf(x0, w1[j * 2 + 0], b1[j]));
        hid[j] = fmaxf(0.f, v);
    }
    u32 o[16];
#pragma unroll
    for (int oo = 0; oo < 16; ++oo) {
        float acc = b2[oo];
#pragma unroll
        for (int j = 0; j < 16; ++j) acc = fmaf(hid[j], w2[oo * 16 + j], acc);
        o[oo] = pack_split(acc);
    }
    u32x4* op = (u32x4*)(out + (size_t)gid * 16);
#pragma unroll
    for (int q = 0; q < 4; ++q) {
        u32x4 v = {o[q * 4 + 0], o[q * 4 + 1], o[q * 4 + 2], o[q * 4 + 3]};
        op[q] = v;
    }
}

// ---------------- LSTM layer: M=4, 256 threads, 2 blocks/CU ----------------
// KT k-tiles of 32 (3 for layer0: x pad 32 + h 64; 4 for layers 1-7).
template <int KT, int IPAD, int I>
__global__ __launch_bounds__(256, 2)
void lstm_m4(const u32* __restrict__ xin,          // packed [row][TT][I]
             const float* __restrict__ w_ih, const float* __restrict__ w_hh,
             const float* __restrict__ b_ih, const float* __restrict__ b_hh,
             u32* __restrict__ hbuf) {              // packed [row][TT][64]
    constexpr int LDPW = KT * 32 + 4;               // panel row stride in u32
    __shared__ __align__(16) u32 panel[2][16 * LDPW];  // rows 4..15 stay 0
    __shared__ float gs[4 * GS];                       // gates [m][n]

    const int tid = threadIdx.x;
    const int wv = tid >> 6, lane = tid & 63, l16 = lane & 15, quad = lane >> 4;
    const int base = blockIdx.x * 4;

    for (int e = tid; e < 2 * 16 * LDPW; e += 256) ((u32*)panel)[e] = 0;

    // --- weights: wave wv owns gate-block wv: n in [64wv, 64wv+64) = 4 n-tiles ---
    bf16x8 bh[KT][4], bl[KT][4];
    float bsum[4];
#pragma unroll
    for (int nt = 0; nt < 4; ++nt) {
        const int n = wv * 64 + nt * 16 + l16;
        bsum[nt] = b_ih[n] + b_hh[n];
#pragma unroll
        for (int kt = 0; kt < KT; ++kt)
#pragma unroll
            for (int jj = 0; jj < 8; ++jj) {
                const int k = kt * 32 + quad * 8 + jj;
                float w = 0.f;
                if (k < I) w = w_ih[n * I + k];
                else if (k >= IPAD) w = w_hh[n * 64 + (k - IPAD)];
                unsigned short h_, l_;
                split2(w, h_, l_);
                bh[kt][nt][jj] = (short)h_;
                bl[kt][nt][jj] = (short)l_;
            }
    }

    float c = 0.f;                       // phase C slot: (m = tid>>6, j = tid&63)
    const int cm = tid >> 6, cj = tid & 63;

    // x staging: thread -> (row am, col ak), one packed u32
    const int am = (I == 64) ? (tid >> 6) : (tid >> 4);
    const int ak = (I == 64) ? (tid & 63) : (tid & 15);
    const bool stg = (I == 64) ? true : (tid < 64);

    u32 xr = 0;
    if (stg) {
        xr = xin[((size_t)(base + am) * TT + 0) * I + ak];
        panel[0][am * LDPW + ak] = xr;
        xr = xin[((size_t)(base + am) * TT + 1) * I + ak];
    }
    __syncthreads();

    for (int t = 0; t < TT; ++t) {
        const int p = t & 1;

        // ---- phase B: gates = bias + [x|h] @ W^T (3-term split-bf16 MFMA) ----
        f32x4 acc[4];
#pragma unroll
        for (int nt = 0; nt < 4; ++nt) {
            acc[nt][0] = bsum[nt]; acc[nt][1] = bsum[nt];
            acc[nt][2] = bsum[nt]; acc[nt][3] = bsum[nt];
        }
#pragma unroll
        for (int kt = 0; kt < KT; ++kt) {
            const int off = l16 * LDPW + kt * 32 + quad * 8;
            const u32x4 a = *(const u32x4*)&panel[p][off];
            const u32x4 b = *(const u32x4*)&panel[p][off + 4];
            bf16x8 fh, fl;
            unpack_frag(a, b, fh, fl);
#pragma unroll
            for (int nt = 0; nt < 4; ++nt) {
                acc[nt] = mfma_bf16(fh, bh[kt][nt], acc[nt]);
                acc[nt] = mfma_bf16(fl, bh[kt][nt], acc[nt]);
                acc[nt] = mfma_bf16(fh, bl[kt][nt], acc[nt]);
            }
        }
        // D row = quad*4+r: real rows 0..3 live in quad 0 only (M=4)
        if (quad == 0) {
#pragma unroll
            for (int nt = 0; nt < 4; ++nt) {
                const int n = wv * 64 + nt * 16 + l16;
#pragma unroll
                for (int r = 0; r < 4; ++r) gs[r * GS + n] = acc[nt][r];
            }
        }
        __syncthreads();  // gs ready

        // ---- phase C: 1 slot/thread, full lanes ----
        {
            const float gi = gs[cm * GS + 0 + cj];
            const float gf = gs[cm * GS + 64 + cj];
            const float gg = gs[cm * GS + 128 + cj];
            const float go = gs[cm * GS + 192 + cj];
            const float iv = sigmoid_fast(gi), fv = sigmoid_fast(gf);
            const float gv = tanh_fast(gg), ov = sigmoid_fast(go);
            c = fv * c + iv * gv;
            const float h = ov * tanh_fast(c);
            const u32 pk = pack_split(h);
            panel[p ^ 1][cm * LDPW + IPAD + cj] = pk;
            hbuf[((size_t)(base + cm) * TT + t) * 64 + cj] = pk;
        }

        // ---- phase A: stage prefetched x(t+1); prefetch x(t+2) (wrapped) ----
        if (stg) {
            panel[p ^ 1][am * LDPW + ak] = xr;
            xr = xin[((size_t)(base + am) * TT + ((t + 2) & (TT - 1))) * I + ak];
        }
        __syncthreads();  // panel[p^1] ready
    }
}

// ---------------- output MLP: 64 -> 32 relu -> 4 (packed input) ----------------
__global__ __launch_bounds__(256)
void mlp_out_kernel(const u32* __restrict__ hin,
                    const float* __restrict__ wo1, const float* __restrict__ bo1,
                    const float* __restrict__ wo2, const float* __restrict__ bo2,
                    float* __restrict__ out) {
    __shared__ __align__(16) float wo1_s[32 * 64];
    __shared__ float bo1_s[32];
    __shared__ float wo2_s[4 * 32];
    __shared__ float bo2_s[4];
    const int tid = threadIdx.x;
    for (int e = tid; e < 32 * 64; e += 256) wo1_s[e] = wo1[e];
    if (tid < 32) bo1_s[tid] = bo1[tid];
    if (tid < 128) wo2_s[tid] = wo2[tid];
    if (tid < 4) bo2_s[tid] = bo2[tid];
    __syncthreads();

    const int gid = blockIdx.x * 256 + tid;
    const u32x4* hv = (const u32x4*)(hin + (size_t)gid * 64);
    float h[64];
#pragma unroll
    for (int q = 0; q < 16; ++q) {
        const u32x4 v = hv[q];
#pragma unroll
        for (int e = 0; e < 4; ++e) {
            const u32 pk = v[e];
            h[q * 4 + e] = __uint_as_float(pk << 16) + __uint_as_float(pk & 0xFFFF0000u);
        }
    }

    float m1[32];
#pragma unroll
    for (int o = 0; o < 32; ++o) {
        float acc = bo1_s[o];
        const float* wrow = wo1_s + o * 64;
#pragma unroll
        for (int q = 0; q < 64; ++q) acc = fmaf(h[q], wrow[q], acc);
        m1[o] = fmaxf(0.f, acc);
    }
    float r[4];
#pragma unroll
    for (int q = 0; q < 4; ++q) {
        float acc = bo2_s[q];
#pragma unroll
        for (int o = 0; o < 32; ++o) acc = fmaf(m1[o], wo2_s[q * 32 + o], acc);
        r[q] = acc;
    }
    float4 res;
    res.x = r[0]; res.y = r[1]; res.z = r[2]; res.w = r[3];
    ((float4*)out)[gid] = res;
}

extern "C" void kernel_launch(void* const* d_in, const int* in_sizes, int n_in,
                              void* d_out, int out_size, void* d_ws, size_t ws_size,
                              hipStream_t stream) {
    const float* x     = (const float*)d_in[0];
    const float* w1    = (const float*)d_in[1];
    const float* b1    = (const float*)d_in[2];
    const float* w2    = (const float*)d_in[3];
    const float* b2    = (const float*)d_in[4];
    const float* w_ih0 = (const float*)d_in[5];
    const float* w_hh0 = (const float*)d_in[6];
    const float* b_ih0 = (const float*)d_in[7];
    const float* b_hh0 = (const float*)d_in[8];
    const float* w_ih  = (const float*)d_in[9];
    const float* w_hh  = (const float*)d_in[10];
    const float* b_ih  = (const float*)d_in[11];
    const float* b_hh  = (const float*)d_in[12];
    const float* wo1   = (const float*)d_in[13];
    const float* bo1   = (const float*)d_in[14];
    const float* wo2   = (const float*)d_in[15];
    const float* bo2   = (const float*)d_in[16];

    // ws: buf_mlp packed [B,T,16] u32 (8.4 MB) | hbuf packed [B,T,64] u32 (33.5 MB)
    u32* buf_mlp = (u32*)d_ws;
    u32* hbuf    = buf_mlp + (size_t)BATCH * TT * 16;

    const int nbt_blocks = (BATCH * TT) / 256;  // 512

    mlp_in_kernel<<<nbt_blocks, 256, 0, stream>>>(x, w1, b1, w2, b2, buf_mlp);

    // layer 0: x-part 16 padded to 32 -> KT=3 (x ktile + 2 h ktiles)
    lstm_m4<3, 32, 16><<<BATCH / 4, 256, 0, stream>>>(buf_mlp, w_ih0, w_hh0, b_ih0, b_hh0, hbuf);
    for (int l = 0; l < 7; ++l) {
        lstm_m4<4, 64, 64><<<BATCH / 4, 256, 0, stream>>>(
            hbuf, w_ih + (size_t)l * 256 * 64, w_hh + (size_t)l * 256 * 64,
            b_ih + (size_t)l * 256, b_hh + (size_t)l * 256, hbuf);
    }

    mlp_out_kernel<<<nbt_blocks, 256, 0, stream>>>(hbuf, wo1, bo1, wo2, bo2, (float*)d_out);
}

// Round 10
// 602.537 us; speedup vs baseline: 1.2668x; 1.2668x over previous
//
#include <hip/hip_runtime.h>

// x[2048,64,2] -> MLP(2->16 relu ->16) -> 8x LSTM(H=64) -> MLP(64->32 relu ->4)
// fp32 in/out. LSTM via split-bf16 MFMA (3-term, ~fp32 accuracy).
//
// Round 10: ALL 8 LSTM layers fused in one kernel; h history lives in LDS.
//   Grid 256 x 256 thr (1 block/CU), M=8 batch rows/block. History
//   hist[m][t][64] packed hi|lo u32, per-m stride 4164 (bank-stagger +4/m:
//   frag reads = 8 accesses/bank, no excess conflict). Layer l step t reads
//   slot t (layer l-1 out) + slot t-1 (own h), phase C overwrites slot t in
//   place; slot 64 stays zero = h(-1). NO global ops in the step loop ->
//   barriers drain LDS only (the r4-r9 chains stalled ~500+ cyc/step on
//   vmcnt(0) drains of h-stores/x-prefetch). Weights re-loaded per layer (L2).

#define BATCH 2048
#define TT 64
#define MSTRIDE 4164   // 65 slots * 64 cols + 4 (bank stagger)

typedef unsigned int u32;
typedef u32 u32x4 __attribute__((ext_vector_type(4)));
typedef short bf16x8 __attribute__((ext_vector_type(8)));
typedef float f32x4 __attribute__((ext_vector_type(4)));

__device__ __forceinline__ float sigmoid_fast(float x) {
    return __builtin_amdgcn_rcpf(1.f + __expf(-x));
}
__device__ __forceinline__ float tanh_fast(float x) {
    float e = __expf(-2.f * x);
    e = fminf(e, 1e30f);
    return (1.f - e) * __builtin_amdgcn_rcpf(1.f + e);
}
// fp32 -> (bf16 hi) | (bf16 lo of exact residual) << 16
__device__ __forceinline__ u32 pack_split(float x) {
    const u32 u = __float_as_uint(x);
    const float r = x - __uint_as_float(u & 0xFFFF0000u);
    return (u >> 16) | (__float_as_uint(r) & 0xFFFF0000u);
}
__device__ __forceinline__ void split2(float x, unsigned short& hi, unsigned short& lo) {
    const u32 u = __float_as_uint(x);
    hi = (unsigned short)(u >> 16);
    const float r = x - __uint_as_float(u & 0xFFFF0000u);
    lo = (unsigned short)(__float_as_uint(r) >> 16);
}
// 8 packed u32 -> hi-frag, lo-frag (bf16x8 each) via v_perm
__device__ __forceinline__ void unpack_frag(const u32x4 a, const u32x4 b, bf16x8& hi, bf16x8& lo) {
    union { bf16x8 v; u32 w[4]; } H, L;
    H.w[0] = __builtin_amdgcn_perm(a.y, a.x, 0x05040100u);
    H.w[1] = __builtin_amdgcn_perm(a.w, a.z, 0x05040100u);
    H.w[2] = __builtin_amdgcn_perm(b.y, b.x, 0x05040100u);
    H.w[3] = __builtin_amdgcn_perm(b.w, b.z, 0x05040100u);
    L.w[0] = __builtin_amdgcn_perm(a.y, a.x, 0x07060302u);
    L.w[1] = __builtin_amdgcn_perm(a.w, a.z, 0x07060302u);
    L.w[2] = __builtin_amdgcn_perm(b.y, b.x, 0x07060302u);
    L.w[3] = __builtin_amdgcn_perm(b.w, b.z, 0x07060302u);
    hi = H.v; lo = L.v;
}
__device__ __forceinline__ f32x4 mfma_bf16(bf16x8 a, bf16x8 b, f32x4 c) {
    return __builtin_amdgcn_mfma_f32_16x16x32_bf16(a, b, c, 0, 0, 0);
}

// ---------------- input MLP: 2 -> 16 relu -> 16 (packed hi/lo out) ----------------
__global__ __launch_bounds__(256)
void mlp_in_kernel(const float* __restrict__ x,
                   const float* __restrict__ w1, const float* __restrict__ b1,
                   const float* __restrict__ w2, const float* __restrict__ b2,
                   u32* __restrict__ out) {
    const int gid = blockIdx.x * 256 + threadIdx.x;
    const float x0 = x[gid * 2 + 0];
    const float x1 = x[gid * 2 + 1];
    float hid[16];
#pragma unroll
    for (int j = 0; j < 16; ++j) {
        float v = fmaf(x1, w1[j * 2 + 1], fmaf(x0, w1[j * 2 + 0], b1[j]));
        hid[j] = fmaxf(0.f, v);
    }
    u32 o[16];
#pragma unroll
    for (int oo = 0; oo < 16; ++oo) {
        float acc = b2[oo];
#pragma unroll
        for (int j = 0; j < 16; ++j) acc = fmaf(hid[j], w2[oo * 16 + j], acc);
        o[oo] = pack_split(acc);
    }
    u32x4* op = (u32x4*)(out + (size_t)gid * 16);
#pragma unroll
    for (int q = 0; q < 4; ++q) {
        u32x4 v = {o[q * 4 + 0], o[q * 4 + 1], o[q * 4 + 2], o[q * 4 + 3]};
        op[q] = v;
    }
}

// ---------------- one fused LSTM layer over the LDS history ----------------
// KT total 32-wide k-tiles; XKT = IPAD/32 of them are the x-part (from slot t),
// the last 2 are the h-part (from slot t-1). I = real x width.
template <int KT, int IPAD, int I>
__device__ __forceinline__ void fused_layer(
    u32* __restrict__ hist,
    const float* __restrict__ w_ih, const float* __restrict__ w_hh,
    const float* __restrict__ b_ih, const float* __restrict__ b_hh) {
    constexpr int XKT = IPAD / 32;
    const int tid = threadIdx.x;
    const int wv = tid >> 6, lane = tid & 63, l16 = lane & 15, quad = lane >> 4;
    const int arow = (l16 & 7) * MSTRIDE;
    const bool hi8 = (l16 >= 8);        // A rows 8..15 read the zero slot
    const int j = wv * 16 + l16;

    // --- weight B-frags: wave wv owns gates i,f,g,o for cols j in [16wv,16wv+16) ---
    bf16x8 bh[KT][4], bl[KT][4];
    float bias[4];
#pragma unroll
    for (int g = 0; g < 4; ++g) {
        const int n = g * 64 + wv * 16 + l16;
        bias[g] = b_ih[n] + b_hh[n];
#pragma unroll
        for (int kt = 0; kt < KT; ++kt)
#pragma unroll
            for (int jj = 0; jj < 8; ++jj) {
                const int k = kt * 32 + quad * 8 + jj;
                float w = 0.f;
                if (k < I) w = w_ih[n * I + k];
                else if (k >= IPAD) w = w_hh[n * 64 + (k - IPAD)];
                unsigned short h_, l_;
                split2(w, h_, l_);
                bh[kt][g][jj] = (short)h_;
                bl[kt][g][jj] = (short)l_;
            }
    }

    float c[4] = {0.f, 0.f, 0.f, 0.f};

    for (int t = 0; t < TT; ++t) {
        const int sx = hi8 ? 64 : t;                       // x-part slot
        const int sh = hi8 ? 64 : (t == 0 ? 64 : t - 1);   // h-part slot

        f32x4 acc[4];
#pragma unroll
        for (int g = 0; g < 4; ++g) {
            acc[g][0] = bias[g]; acc[g][1] = bias[g];
            acc[g][2] = bias[g]; acc[g][3] = bias[g];
        }
        // x-part k-tiles (slot t: layer l-1 output, pre-overwrite)
#pragma unroll
        for (int kt = 0; kt < XKT; ++kt) {
            const int off = arow + sx * 64 + kt * 32 + quad * 8;
            const u32x4 a = *(const u32x4*)&hist[off];
            const u32x4 b = *(const u32x4*)&hist[off + 4];
            bf16x8 fh, fl;
            unpack_frag(a, b, fh, fl);
#pragma unroll
            for (int g = 0; g < 4; ++g) {
                acc[g] = mfma_bf16(fh, bh[kt][g], acc[g]);
                acc[g] = mfma_bf16(fl, bh[kt][g], acc[g]);
                acc[g] = mfma_bf16(fh, bl[kt][g], acc[g]);
            }
        }
        // h-part k-tiles (slot t-1: this layer's h)
#pragma unroll
        for (int kt = 0; kt < 2; ++kt) {
            const int off = arow + sh * 64 + kt * 32 + quad * 8;
            const u32x4 a = *(const u32x4*)&hist[off];
            const u32x4 b = *(const u32x4*)&hist[off + 4];
            bf16x8 fh, fl;
            unpack_frag(a, b, fh, fl);
#pragma unroll
            for (int g = 0; g < 4; ++g) {
                acc[g] = mfma_bf16(fh, bh[XKT + kt][g], acc[g]);
                acc[g] = mfma_bf16(fl, bh[XKT + kt][g], acc[g]);
                acc[g] = mfma_bf16(fh, bl[XKT + kt][g], acc[g]);
            }
        }
        __syncthreads();  // all reads of slot t done (LDS-only drain)

        // phase C: reg-local; D row = quad*4+r, rows 0..7 real -> quads 0-1
        if (quad < 2) {
#pragma unroll
            for (int r = 0; r < 4; ++r) {
                const int m = quad * 4 + r;
                const float iv = sigmoid_fast(acc[0][r]);
                const float fv = sigmoid_fast(acc[1][r]);
                const float gv = tanh_fast(acc[2][r]);
                const float ov = sigmoid_fast(acc[3][r]);
                c[r] = fv * c[r] + iv * gv;
                const float h = ov * tanh_fast(c[r]);
                hist[m * MSTRIDE + t * 64 + j] = pack_split(h);  // overwrite slot t
            }
        }
        __syncthreads();  // slot t writes visible for step t+1
    }
}

// ---------------- fused 8-layer LSTM ----------------
__global__ __launch_bounds__(256, 1)
void lstm_fused(const u32* __restrict__ buf_mlp,
                const float* __restrict__ w_ih0, const float* __restrict__ w_hh0,
                const float* __restrict__ b_ih0, const float* __restrict__ b_hh0,
                const float* __restrict__ w_ih, const float* __restrict__ w_hh,
                const float* __restrict__ b_ih, const float* __restrict__ b_hh,
                u32* __restrict__ hbuf) {
    __shared__ __align__(16) u32 hist[8 * MSTRIDE];   // 133 KB
    const int tid = threadIdx.x;
    const int base = blockIdx.x * 8;

    // zero history (incl. slot 64 = permanent h(-1)=0)
    for (int e = tid; e < 8 * MSTRIDE; e += 256) hist[e] = 0;
    __syncthreads();
    // preload layer-0 input (packed, 16 cols) into slots 0..63
    for (int idx = tid; idx < 8 * 64 * 16; idx += 256) {
        const int m = idx >> 10, rem = idx & 1023, s = rem >> 4, k = rem & 15;
        hist[m * MSTRIDE + s * 64 + k] =
            buf_mlp[((size_t)(base + m) * TT + s) * 16 + k];
    }
    __syncthreads();

    fused_layer<3, 32, 16>(hist, w_ih0, w_hh0, b_ih0, b_hh0);
#pragma unroll 1
    for (int l = 0; l < 7; ++l) {
        fused_layer<4, 64, 64>(hist,
                               w_ih + (size_t)l * 256 * 64, w_hh + (size_t)l * 256 * 64,
                               b_ih + (size_t)l * 256, b_hh + (size_t)l * 256);
    }

    // final history (layer-8 output) -> global, coalesced b128
    for (int idx = tid; idx < 8192; idx += 256) {
        const int m = idx >> 10, off = (idx & 1023) * 4;
        *(u32x4*)&hbuf[(size_t)(base + m) * 4096 + off] =
            *(const u32x4*)&hist[m * MSTRIDE + off];
    }
}

// ---------------- output MLP: 64 -> 32 relu -> 4 (packed input) ----------------
__global__ __launch_bounds__(256)
void mlp_out_kernel(const u32* __restrict__ hin,
                    const float* __restrict__ wo1, const float* __restrict__ bo1,
                    const float* __restrict__ wo2, const float* __restrict__ bo2,
                    float* __restrict__ out) {
    __shared__ __align__(16) float wo1_s[32 * 64];
    __shared__ float bo1_s[32];
    __shared__ float wo2_s[4 * 32];
    __shared__ float bo2_s[4];
    const int tid = threadIdx.x;
    for (int e = tid; e < 32 * 64; e += 256) wo1_s[e] = wo1[e];
    if (tid < 32) bo1_s[tid] = bo1[tid];
    if (tid < 128) wo2_s[tid] = wo2[tid];
    if (tid < 4) bo2_s[tid] = bo2[tid];
    __syncthreads();

    const int gid = blockIdx.x * 256 + tid;
    const u32x4* hv = (const u32x4*)(hin + (size_t)gid * 64);
    float h[64];
#pragma unroll
    for (int q = 0; q < 16; ++q) {
        const u32x4 v = hv[q];
#pragma unroll
        for (int e = 0; e < 4; ++e) {
            const u32 pk = v[e];
            h[q * 4 + e] = __uint_as_float(pk << 16) + __uint_as_float(pk & 0xFFFF0000u);
        }
    }

    float m1[32];
#pragma unroll
    for (int o = 0; o < 32; ++o) {
        float acc = bo1_s[o];
        const float* wrow = wo1_s + o * 64;
#pragma unroll
        for (int q = 0; q < 64; ++q) acc = fmaf(h[q], wrow[q], acc);
        m1[o] = fmaxf(0.f, acc);
    }
    float r[4];
#pragma unroll
    for (int q = 0; q < 4; ++q) {
        float acc = bo2_s[q];
#pragma unroll
        for (int o = 0; o < 32; ++o) acc = fmaf(m1[o], wo2_s[q * 32 + o], acc);
        r[q] = acc;
    }
    float4 res;
    res.x = r[0]; res.y = r[1]; res.z = r[2]; res.w = r[3];
    ((float4*)out)[gid] = res;
}

extern "C" void kernel_launch(void* const* d_in, const int* in_sizes, int n_in,
                              void* d_out, int out_size, void* d_ws, size_t ws_size,
                              hipStream_t stream) {
    const float* x     = (const float*)d_in[0];
    const float* w1    = (const float*)d_in[1];
    const float* b1    = (const float*)d_in[2];
    const float* w2    = (const float*)d_in[3];
    const float* b2    = (const float*)d_in[4];
    const float* w_ih0 = (const float*)d_in[5];
    const float* w_hh0 = (const float*)d_in[6];
    const float* b_ih0 = (const float*)d_in[7];
    const float* b_hh0 = (const float*)d_in[8];
    const float* w_ih  = (const float*)d_in[9];
    const float* w_hh  = (const float*)d_in[10];
    const float* b_ih  = (const float*)d_in[11];
    const float* b_hh  = (const float*)d_in[12];
    const float* wo1   = (const float*)d_in[13];
    const float* bo1   = (const float*)d_in[14];
    const float* wo2   = (const float*)d_in[15];
    const float* bo2   = (const float*)d_in[16];

    // ws: buf_mlp packed [B,T,16] u32 (8.4 MB) | hbuf packed [B,T,64] u32 (33.5 MB)
    u32* buf_mlp = (u32*)d_ws;
    u32* hbuf    = buf_mlp + (size_t)BATCH * TT * 16;

    const int nbt_blocks = (BATCH * TT) / 256;  // 512

    mlp_in_kernel<<<nbt_blocks, 256, 0, stream>>>(x, w1, b1, w2, b2, buf_mlp);

    lstm_fused<<<BATCH / 8, 256, 0, stream>>>(buf_mlp, w_ih0, w_hh0, b_ih0, b_hh0,
                                              w_ih, w_hh, b_ih, b_hh, hbuf);

    mlp_out_kernel<<<nbt_blocks, 256, 0, stream>>>(hbuf, wo1, bo1, wo2, bo2, (float*)d_out);
}